// Round 9
// baseline (784.404 us; speedup 1.0000x reference)
//
#include <hip/hip_runtime.h>
#include <math.h>

#define BB 64
#define TT 2048
#define FF 128
#define HH 32
#define GG 128  // 4*H

// gate-column prescale: sigma(a) = rcp(1 + exp2(S1*a)), tanh(a) = 2*rcp(1+exp2(S2*a))-1
#define S1f (-1.4426950408889634f)  // -log2(e)
#define S2f (-2.8853900817779268f)  // -2*log2(e)

typedef _Float16 half2_t __attribute__((ext_vector_type(2)));

__device__ __forceinline__ unsigned h2u(half2_t v) {
    unsigned u; __builtin_memcpy(&u, &v, 4); return u;
}
__device__ __forceinline__ half2_t u2h(unsigned u) {
    half2_t v; __builtin_memcpy(&v, &u, 4); return v;
}
__device__ __forceinline__ half2_t pkrtz(float a, float b) {
    auto r = __builtin_amdgcn_cvt_pkrtz(a, b);  // __fp16 vec2, same bits
    half2_t v; __builtin_memcpy(&v, &r, 4); return v;
}
__device__ __forceinline__ float rcp_(float x) { return __builtin_amdgcn_rcpf(x); }
__device__ __forceinline__ float exp2_(float x) { return __builtin_amdgcn_exp2f(x); }

// DPP lane shuffles (within rows of 16 / quads); bound_ctrl=1, all rows/banks
#define DPP_(x, ctrl) \
    ((unsigned)__builtin_amdgcn_mov_dpp((int)(x), (ctrl), 0xF, 0xF, true))
#define CTRL_XOR1 0xB1  // quad_perm [1,0,3,2]
#define CTRL_XOR2 0x4E  // quad_perm [2,3,0,1]
#define CTRL_ROR4 0x124 // row_ror:4
#define CTRL_ROR8 0x128 // row_ror:8
// ds_swizzle bit-mode xor16 within 32-lane groups: (16<<10)|0x1F
#define SWZ16_(x) ((unsigned)__builtin_amdgcn_ds_swizzle((int)(x), 0x401F))

#if __has_builtin(__builtin_amdgcn_permlane16_swap)
#define HAVE_PL16 1
#else
#define HAVE_PL16 0
#endif

// Build the 16-reg all-gather tree from seed reg v0 (packed pair or index).
// Same tree runs on indices at setup (discovery) and on h each step, so only
// the permutation's *fixedness* matters, not its exact semantics.
__device__ __forceinline__ void gather_tree(unsigned v0, unsigned g[16]) {
    unsigned v1 = DPP_(v0, CTRL_XOR2);
#if HAVE_PL16
    auto sw = __builtin_amdgcn_permlane16_swap(v0, v1, false, false);
    unsigned s0 = (unsigned)sw[0], s1 = (unsigned)sw[1];
    g[0] = s0;
    g[1] = s1;
    g[2] = DPP_(s0, CTRL_XOR2);
    g[3] = DPP_(s1, CTRL_XOR2);
#else
    g[0] = v0;
    g[1] = v1;
    g[2] = SWZ16_(v0);
    g[3] = SWZ16_(v1);
#endif
#pragma unroll
    for (int r = 0; r < 4; ++r) g[4 + r] = DPP_(g[r], CTRL_ROR4);
#pragma unroll
    for (int r = 0; r < 8; ++r) g[8 + r] = DPP_(g[r], CTRL_ROR8);
}

// ---- Kernel 1: xg2[b][j][t] = half2( S*(X@Wx+b)[col j], S*(X@Wx+b)[col j+64] )
// packed fp16 pairs, [64 cols][2048 t] per batch, 4B per (j,t).
__global__ __launch_bounds__(256) void xg_gemm(const float* __restrict__ X,
                                               const float* __restrict__ Wx,
                                               const float* __restrict__ bias,
                                               unsigned* __restrict__ xg2) {
    __shared__ float XL[64 * 32];    // [row][fi]  8 KB
    __shared__ float WL[32 * 128];   // [fi][col] 16 KB
    const int tid = threadIdx.x;
    const int row0 = blockIdx.x * 64;   // flattened b*T + t0 (one b per block)
    const int j0 = (tid & 15) * 4;   // 4 X-cols (j0..j0+3) + 4 Y-cols (+64)
    const int r0 = (tid >> 4) * 4;   // 4 output rows (consecutive t)

    float acc[4][8];                 // [row][4 X + 4 Y]
#pragma unroll
    for (int r = 0; r < 4; ++r)
#pragma unroll
        for (int jj = 0; jj < 8; ++jj) acc[r][jj] = 0.f;

    for (int f0 = 0; f0 < FF; f0 += 32) {
        __syncthreads();
        {
            const float4* src = (const float4*)(Wx + f0 * GG);
            float4* dst = (float4*)WL;
            dst[tid]       = src[tid];
            dst[tid + 256] = src[tid + 256];
            dst[tid + 512] = src[tid + 512];
            dst[tid + 768] = src[tid + 768];
        }
        {
            int lin = tid * 4;
            int row = lin >> 5;
            int fi  = lin & 31;
            ((float4*)XL)[tid] =
                *(const float4*)(X + (size_t)(row0 + row) * FF + f0 + fi);
            lin = (tid + 256) * 4;
            row = lin >> 5;
            fi  = lin & 31;
            ((float4*)XL)[tid + 256] =
                *(const float4*)(X + (size_t)(row0 + row) * FF + f0 + fi);
        }
        __syncthreads();
#pragma unroll 4
        for (int fi = 0; fi < 32; ++fi) {
            float xv[4];
#pragma unroll
            for (int r = 0; r < 4; ++r) xv[r] = XL[(r0 + r) * 32 + fi];
            float4 w0 = *(float4*)&WL[fi * GG + j0];        // X cols
            float4 w1 = *(float4*)&WL[fi * GG + j0 + 64];   // Y cols
            float w[8] = {w0.x, w0.y, w0.z, w0.w, w1.x, w1.y, w1.z, w1.w};
#pragma unroll
            for (int r = 0; r < 4; ++r)
#pragma unroll
                for (int jj = 0; jj < 8; ++jj)
                    acc[r][jj] = fmaf(xv[r], w[jj], acc[r][jj]);
        }
    }
    const int b  = row0 >> 11;            // row0 / 2048
    const int t0 = (row0 & 2047) + r0;
#pragma unroll
    for (int jj = 0; jj < 4; ++jj) {
        const int j = j0 + jj;
        const float bX = bias[j];
        const float bY = bias[j + 64];
        const float sY = (j < 32) ? S2f : S1f;  // col j+64: g if <96 else o
        uint4 o;
        o.x = h2u(pkrtz((acc[0][jj] + bX) * S1f, (acc[0][jj + 4] + bY) * sY));
        o.y = h2u(pkrtz((acc[1][jj] + bX) * S1f, (acc[1][jj + 4] + bY) * sY));
        o.z = h2u(pkrtz((acc[2][jj] + bX) * S1f, (acc[2][jj + 4] + bY) * sY));
        o.w = h2u(pkrtz((acc[3][jj] + bX) * S1f, (acc[3][jj + 4] + bY) * sY));
        *(uint4*)(xg2 + (size_t)(b * 64 + j) * TT + t0) = o;
    }
}

// ---- Kernel 2: LSTM scan, 2 chains per wave, explicit software pipeline ---
// One wave per block; block handles batches 2*bid (A) and 2*bid+1 (B).
// Per sub-step emit: B_matvec(t), A_act(t), B_act(t), A_matvec(t+1) — every
// consumer is ~100 issue-cycles after its producer, hiding dep-chain stalls
// on the in-order SIMD. All cross-lane traffic is VALU (DPP/permlane).
__global__ __launch_bounds__(64) void lstm_rec(const unsigned* __restrict__ xg2,
                                               const float* __restrict__ Wh,
                                               const float* __restrict__ Wd,
                                               const float* __restrict__ bd,
                                               float* __restrict__ out) {
    const int l = threadIdx.x;  // 0..63
    const int m = l & 31;
    const bool lo = (l < HH);
    const int b0 = blockIdx.x * 2;

    // ---- discover gather permutation: run the tree on the index ----
    unsigned iv[16];
    gather_tree((unsigned)m, iv);

    // ---- load Wh columns l and l+64, permuted + prescaled + fp16-packed ---
    const float scx = S1f;                 // col l: i (lo) or f (hi) -> sigmoid
    const float scy = lo ? S2f : S1f;      // col l+64: g (lo, tanh) or o (hi)
    half2_t whx[16], why[16];
#pragma unroll
    for (int r = 0; r < 16; ++r) {
        const int p  = (int)(iv[r] & 31u);
        const int p2 = p ^ 1;
        whx[r] = pkrtz(Wh[p * GG + l] * scx,       Wh[p2 * GG + l] * scx);
        why[r] = pkrtz(Wh[p * GG + l + 64] * scy,  Wh[p2 * GG + l + 64] * scy);
    }

    // per-lane affine for act1: tanh = 2*s-1 (lo), sigmoid = s (hi)
    const float A1 = lo ? 2.f : 1.f;
    const float B1 = lo ? -1.f : 0.f;

    float hA = 0.f, cA = 0.f, hB = 0.f, cB = 0.f;

    const unsigned* pA = xg2 + (size_t)(b0 * 64 + l) * TT;
    const unsigned* pB = xg2 + (size_t)((b0 + 1) * 64 + l) * TT;

    uint4 curA = *(const uint4*)(pA);
    uint4 curB = *(const uint4*)(pB);
    uint4 nxtA = *(const uint4*)(pA + 4);
    uint4 nxtB = *(const uint4*)(pB + 4);

    auto matvec = [&](float hq, unsigned xin, float& a0, float& a1)
        __attribute__((always_inline)) {
        unsigned hn = DPP_(__float_as_uint(hq), CTRL_XOR1);  // h[m^1]
        unsigned g0 = h2u(pkrtz(hq, __uint_as_float(hn)));   // (h[m], h[m^1])
        unsigned g[16];
        gather_tree(g0, g);
        half2_t xv = u2h(xin);
        float ax[4] = {(float)xv[0], 0.f, 0.f, 0.f};
        float ay[4] = {(float)xv[1], 0.f, 0.f, 0.f};
#pragma unroll
        for (int r = 0; r < 16; ++r) {
            half2_t hp = u2h(g[r]);
            ax[r & 3] = __builtin_amdgcn_fdot2(hp, whx[r], ax[r & 3], false);
            ay[r & 3] = __builtin_amdgcn_fdot2(hp, why[r], ay[r & 3], false);
        }
        a0 = (ax[0] + ax[1]) + (ax[2] + ax[3]);
        a1 = (ay[0] + ay[1]) + (ay[2] + ay[3]);
    };

    auto actupd = [&](float& hq, float& cq, float a0, float a1)
        __attribute__((always_inline)) {
        float act0 = rcp_(1.f + exp2_(a0));                 // sigmoid (i|f)
        float act1 = fmaf(A1, rcp_(1.f + exp2_(a1)), B1);   // tanh g | sig o
        // two independent half-swaps: p={i|g} q={f|o} u={g|i} v={o|f}
        auto pq = __builtin_amdgcn_permlane32_swap(__float_as_uint(act0),
                                                   __float_as_uint(act1), false, false);
        auto uv = __builtin_amdgcn_permlane32_swap(__float_as_uint(act1),
                                                   __float_as_uint(act0), false, false);
        float p = __uint_as_float(pq[0]);
        float q = __uint_as_float(pq[1]);
        float u = __uint_as_float(uv[0]);
        float v = __uint_as_float(uv[1]);
        float f_all = lo ? q : act0;   // sigmoid(f)
        float o_all = lo ? v : act1;   // sigmoid(o)
        cq = fmaf(f_all, cq, u * p);   // u*p = i*g in every lane
        float tc = fmaf(2.f, rcp_(1.f + exp2_(cq * S2f)), -1.f);  // tanh(c)
        hq = o_all * tc;
    };

    float a0A, a1A, a0B, a1B;
    matvec(hA, curA.x, a0A, a1A);   // A is one matvec ahead (t=0)

#pragma unroll 1
    for (int t4 = 0; t4 < TT; t4 += 4) {
        uint4 uA = curA, uB = curB;
        curA = nxtA; curB = nxtB;
        if (t4 + 8 < TT) {
            nxtA = *(const uint4*)(pA + t4 + 8);
            nxtB = *(const uint4*)(pB + t4 + 8);
        }
        // s = 0 (t = t4)
        matvec(hB, uB.x, a0B, a1B);
        actupd(hA, cA, a0A, a1A);
        actupd(hB, cB, a0B, a1B);
        matvec(hA, uA.y, a0A, a1A);         // t+1
        // s = 1
        matvec(hB, uB.y, a0B, a1B);
        actupd(hA, cA, a0A, a1A);
        actupd(hB, cB, a0B, a1B);
        matvec(hA, uA.z, a0A, a1A);
        // s = 2
        matvec(hB, uB.z, a0B, a1B);
        actupd(hA, cA, a0A, a1A);
        actupd(hB, cB, a0B, a1B);
        matvec(hA, uA.w, a0A, a1A);
        // s = 3
        matvec(hB, uB.w, a0B, a1B);
        actupd(hA, cA, a0A, a1A);
        actupd(hB, cB, a0B, a1B);
        if (t4 + 4 < TT)
            matvec(hA, curA.x, a0A, a1A);   // t4+4 (curA rotated above)
    }

    // out[b] = h_T @ Wd + bd   (each h[k] appears twice across 64 lanes)
    const float wd = Wd[m];
    float ca = hA * wd;
    float cb = hB * wd;
#pragma unroll
    for (int off = 32; off >= 1; off >>= 1) {
        ca += __shfl_xor(ca, off, 64);
        cb += __shfl_xor(cb, off, 64);
    }
    if (l == 0) {
        out[b0]     = fmaf(0.5f, ca, bd[0]);
        out[b0 + 1] = fmaf(0.5f, cb, bd[0]);
    }
}

extern "C" void kernel_launch(void* const* d_in, const int* in_sizes, int n_in,
                              void* d_out, int out_size, void* d_ws, size_t ws_size,
                              hipStream_t stream) {
    const float* X    = (const float*)d_in[0];
    const float* Wx   = (const float*)d_in[1];
    const float* Wh   = (const float*)d_in[2];
    const float* bias = (const float*)d_in[3];
    const float* Wd   = (const float*)d_in[4];
    const float* bd   = (const float*)d_in[5];
    float* out = (float*)d_out;
    unsigned* xg2 = (unsigned*)d_ws;  // [64][64][2048] half2-pairs = 32 MB

    hipLaunchKernelGGL(xg_gemm, dim3((BB * TT) / 64), dim3(256), 0, stream,
                       X, Wx, bias, xg2);
    hipLaunchKernelGGL(lstm_rec, dim3(BB / 2), dim3(64), 0, stream,
                       xg2, Wh, Wd, bd, out);
}

// Round 10
// 610.965 us; speedup vs baseline: 1.2839x; 1.2839x over previous
//
#include <hip/hip_runtime.h>
#include <math.h>

#define BB 64
#define TT 2048
#define FF 128
#define HH 32
#define GG 128  // 4*H

// gate-column prescale: sigma(a) = rcp(1 + exp2(S1*a)), tanh(a) = 2*rcp(1+exp2(S2*a))-1
#define S1f (-1.4426950408889634f)  // -log2(e)
#define S2f (-2.8853900817779268f)  // -2*log2(e)

typedef _Float16 half2_t __attribute__((ext_vector_type(2)));

__device__ __forceinline__ unsigned h2u(half2_t v) {
    unsigned u; __builtin_memcpy(&u, &v, 4); return u;
}
__device__ __forceinline__ half2_t u2h(unsigned u) {
    half2_t v; __builtin_memcpy(&v, &u, 4); return v;
}
__device__ __forceinline__ half2_t pkrtz(float a, float b) {
    auto r = __builtin_amdgcn_cvt_pkrtz(a, b);  // __fp16 vec2, same bits
    half2_t v; __builtin_memcpy(&v, &r, 4); return v;
}
__device__ __forceinline__ float rcp_(float x) { return __builtin_amdgcn_rcpf(x); }
__device__ __forceinline__ float exp2_(float x) { return __builtin_amdgcn_exp2f(x); }

// DPP lane shuffles (within rows of 16 / quads); bound_ctrl=1, all rows/banks
#define DPP_(x, ctrl) \
    ((unsigned)__builtin_amdgcn_mov_dpp((int)(x), (ctrl), 0xF, 0xF, true))
#define CTRL_XOR1 0xB1  // quad_perm [1,0,3,2]
#define CTRL_XOR2 0x4E  // quad_perm [2,3,0,1]
#define CTRL_ROR4 0x124 // row_ror:4
#define CTRL_ROR8 0x128 // row_ror:8
// ds_swizzle bit-mode xor16 within 32-lane groups: (16<<10)|0x1F
#define SWZ16_(x) ((unsigned)__builtin_amdgcn_ds_swizzle((int)(x), 0x401F))

#if __has_builtin(__builtin_amdgcn_permlane16_swap)
#define HAVE_PL16 1
#else
#define HAVE_PL16 0
#endif

// Build the 16-reg all-gather tree from seed reg v0 (packed pair or index).
// ALL ops stay within 32-lane groups (quads / rows of 16 / row-pair swap), so
// each wave half gathers its own group's 32 values independently. The same
// tree runs on indices at setup (discovery) and on h each step, so only the
// permutation's *fixedness* matters, not its exact semantics.
__device__ __forceinline__ void gather_tree(unsigned v0, unsigned g[16]) {
    unsigned v1 = DPP_(v0, CTRL_XOR2);
#if HAVE_PL16
    auto sw = __builtin_amdgcn_permlane16_swap(v0, v1, false, false);
    unsigned s0 = (unsigned)sw[0], s1 = (unsigned)sw[1];
    g[0] = s0;
    g[1] = s1;
    g[2] = DPP_(s0, CTRL_XOR2);
    g[3] = DPP_(s1, CTRL_XOR2);
#else
    g[0] = v0;
    g[1] = v1;
    g[2] = SWZ16_(v0);
    g[3] = SWZ16_(v1);
#endif
#pragma unroll
    for (int r = 0; r < 4; ++r) g[4 + r] = DPP_(g[r], CTRL_ROR4);
#pragma unroll
    for (int r = 0; r < 8; ++r) g[8 + r] = DPP_(g[r], CTRL_ROR8);
}

// ---- Kernel 1: xgP[b][m][t] = uint2( h2(i',f'), h2(g',o') ), prescaled fp16.
// i'=S1*(X@Wx+b)[m], f'=S1*[m+32], g'=S2*[m+64], o'=S1*[m+96].
__global__ __launch_bounds__(256) void xg_gemm(const float* __restrict__ X,
                                               const float* __restrict__ Wx,
                                               const float* __restrict__ bias,
                                               unsigned* __restrict__ xgP) {
    __shared__ float XL[64 * 32];    // [row][fi]  8 KB
    __shared__ float WL[32 * 128];   // [fi][col] 16 KB
    const int tid = threadIdx.x;
    const int row0 = blockIdx.x * 64;   // flattened b*T + t0 (one b per block)
    const int m0 = (tid & 15) * 2;   // 2 hidden units, 4 gate cols each
    const int r0 = (tid >> 4) * 4;   // 4 output rows (consecutive t)

    float acc[4][8];                 // [row][{I0,I1,F0,F1,G0,G1,O0,O1}]
#pragma unroll
    for (int r = 0; r < 4; ++r)
#pragma unroll
        for (int jj = 0; jj < 8; ++jj) acc[r][jj] = 0.f;

    for (int f0 = 0; f0 < FF; f0 += 32) {
        __syncthreads();
        {
            const float4* src = (const float4*)(Wx + f0 * GG);
            float4* dst = (float4*)WL;
            dst[tid]       = src[tid];
            dst[tid + 256] = src[tid + 256];
            dst[tid + 512] = src[tid + 512];
            dst[tid + 768] = src[tid + 768];
        }
        {
            int lin = tid * 4;
            int row = lin >> 5;
            int fi  = lin & 31;
            ((float4*)XL)[tid] =
                *(const float4*)(X + (size_t)(row0 + row) * FF + f0 + fi);
            lin = (tid + 256) * 4;
            row = lin >> 5;
            fi  = lin & 31;
            ((float4*)XL)[tid + 256] =
                *(const float4*)(X + (size_t)(row0 + row) * FF + f0 + fi);
        }
        __syncthreads();
#pragma unroll 4
        for (int fi = 0; fi < 32; ++fi) {
            float xv[4];
#pragma unroll
            for (int r = 0; r < 4; ++r) xv[r] = XL[(r0 + r) * 32 + fi];
            float2 wI = *(float2*)&WL[fi * GG + m0];
            float2 wF = *(float2*)&WL[fi * GG + m0 + 32];
            float2 wG = *(float2*)&WL[fi * GG + m0 + 64];
            float2 wO = *(float2*)&WL[fi * GG + m0 + 96];
            float w[8] = {wI.x, wI.y, wF.x, wF.y, wG.x, wG.y, wO.x, wO.y};
#pragma unroll
            for (int r = 0; r < 4; ++r)
#pragma unroll
                for (int jj = 0; jj < 8; ++jj)
                    acc[r][jj] = fmaf(xv[r], w[jj], acc[r][jj]);
        }
    }
    const int b  = row0 >> 11;            // row0 / 2048
    const int t0 = (row0 & 2047) + r0;
#pragma unroll
    for (int mm = 0; mm < 2; ++mm) {
        const int m = m0 + mm;
        const float bI = bias[m];
        const float bF = bias[m + 32];
        const float bG = bias[m + 64];
        const float bO = bias[m + 96];
        unsigned w0[4], w1[4];
#pragma unroll
        for (int r = 0; r < 4; ++r) {
            w0[r] = h2u(pkrtz((acc[r][0 + mm] + bI) * S1f,
                              (acc[r][2 + mm] + bF) * S1f));
            w1[r] = h2u(pkrtz((acc[r][4 + mm] + bG) * S2f,
                              (acc[r][6 + mm] + bO) * S1f));
        }
        unsigned* dst = xgP + ((size_t)(b * HH + m) * TT + t0) * 2;
        *(uint4*)(dst)     = make_uint4(w0[0], w1[0], w0[1], w1[1]);
        *(uint4*)(dst + 4) = make_uint4(w0[2], w1[2], w0[3], w1[3]);
    }
}

// ---- Kernel 2: LSTM scan, 2 chains per wave in DISJOINT LANE HALVES ------
// Lanes 0-31 = batch 2*bid, lanes 32-63 = batch 2*bid+1. Lane (grp,m) owns
// all four gates {i,f,g,o}[m]: gate combine is lane-local (no cross-half
// traffic). h all-gather per 32-lane group via the within-group butterfly.
__global__ __launch_bounds__(64) void lstm_rec(const unsigned* __restrict__ xgP,
                                               const float* __restrict__ Wh,
                                               const float* __restrict__ Wd,
                                               const float* __restrict__ bd,
                                               float* __restrict__ out) {
    const int l = threadIdx.x;   // 0..63
    const int m = l & 31;        // hidden index
    const int grp = l >> 5;      // 0: batch b0, 1: batch b0+1
    const int b = blockIdx.x * 2 + grp;

    // ---- discover gather permutation: run the tree on the index ----
    unsigned iv[16];
    gather_tree((unsigned)m, iv);

    // ---- load Wh rows, permuted + prescaled + fp16-packed, 4 gate cols ----
    half2_t whI[16], whF[16], whG[16], whO[16];
#pragma unroll
    for (int r = 0; r < 16; ++r) {
        const int p  = (int)(iv[r] & 31u);
        const int p2 = p ^ 1;
        whI[r] = pkrtz(Wh[p * GG + m]      * S1f, Wh[p2 * GG + m]      * S1f);
        whF[r] = pkrtz(Wh[p * GG + m + 32] * S1f, Wh[p2 * GG + m + 32] * S1f);
        whG[r] = pkrtz(Wh[p * GG + m + 64] * S2f, Wh[p2 * GG + m + 64] * S2f);
        whO[r] = pkrtz(Wh[p * GG + m + 96] * S1f, Wh[p2 * GG + m + 96] * S1f);
    }

    float h = 0.f;  // h[m] of batch b
    float c = 0.f;

    const uint4* pX = (const uint4*)(xgP + (size_t)(b * HH + m) * TT * 2);
    uint4 cur0 = pX[0];   // t 0..1   (per t: wIF, wGO)
    uint4 cur1 = pX[1];   // t 2..3
    uint4 nxt0 = pX[2];
    uint4 nxt1 = pX[3];

    auto step = [&](unsigned wIF, unsigned wGO) __attribute__((always_inline)) {
        // within-group all-gather: h -> 16 packed half2
        unsigned hn = DPP_(__float_as_uint(h), CTRL_XOR1);   // h[m^1]
        unsigned g0 = h2u(pkrtz(h, __uint_as_float(hn)));    // (h[m], h[m^1])
        unsigned g[16];
        gather_tree(g0, g);

        half2_t xIF = u2h(wIF);
        half2_t xGO = u2h(wGO);
        float aI0 = (float)xIF[0], aI1 = 0.f;
        float aF0 = (float)xIF[1], aF1 = 0.f;
        float aG0 = (float)xGO[0], aG1 = 0.f;
        float aO0 = (float)xGO[1], aO1 = 0.f;
#pragma unroll
        for (int r = 0; r < 16; r += 2) {
            half2_t hp0 = u2h(g[r]);
            half2_t hp1 = u2h(g[r + 1]);
            aI0 = __builtin_amdgcn_fdot2(hp0, whI[r],     aI0, false);
            aI1 = __builtin_amdgcn_fdot2(hp1, whI[r + 1], aI1, false);
            aF0 = __builtin_amdgcn_fdot2(hp0, whF[r],     aF0, false);
            aF1 = __builtin_amdgcn_fdot2(hp1, whF[r + 1], aF1, false);
            aG0 = __builtin_amdgcn_fdot2(hp0, whG[r],     aG0, false);
            aG1 = __builtin_amdgcn_fdot2(hp1, whG[r + 1], aG1, false);
            aO0 = __builtin_amdgcn_fdot2(hp0, whO[r],     aO0, false);
            aO1 = __builtin_amdgcn_fdot2(hp1, whO[r + 1], aO1, false);
        }
        float aI = aI0 + aI1;
        float aF = aF0 + aF1;
        float aG = aG0 + aG1;
        float aO = aO0 + aO1;

        float si = rcp_(1.f + exp2_(aI));                 // sigmoid(i)
        float sf = rcp_(1.f + exp2_(aF));                 // sigmoid(f)
        float tg = fmaf(2.f, rcp_(1.f + exp2_(aG)), -1.f);// tanh(g)
        float so = rcp_(1.f + exp2_(aO));                 // sigmoid(o)

        c = fmaf(sf, c, si * tg);
        float tc = fmaf(2.f, rcp_(1.f + exp2_(c * S2f)), -1.f);  // tanh(c)
        h = so * tc;
    };

#pragma unroll 1
    for (int t4 = 0; t4 < TT; t4 += 4) {
        uint4 u0 = cur0, u1 = cur1;
        cur0 = nxt0; cur1 = nxt1;
        if (t4 + 8 < TT) {
            nxt0 = pX[t4 / 2 + 4];
            nxt1 = pX[t4 / 2 + 5];
        }
        step(u0.x, u0.y);
        step(u0.z, u0.w);
        step(u1.x, u1.y);
        step(u1.z, u1.w);
    }

    // out[b] = h @ Wd + bd: reduce within each 32-lane group
    float ca = h * Wd[m];
#pragma unroll
    for (int off = 16; off >= 1; off >>= 1)
        ca += __shfl_xor(ca, off, 64);
    if (m == 0) out[b] = ca + bd[0];
}

extern "C" void kernel_launch(void* const* d_in, const int* in_sizes, int n_in,
                              void* d_out, int out_size, void* d_ws, size_t ws_size,
                              hipStream_t stream) {
    const float* X    = (const float*)d_in[0];
    const float* Wx   = (const float*)d_in[1];
    const float* Wh   = (const float*)d_in[2];
    const float* bias = (const float*)d_in[3];
    const float* Wd   = (const float*)d_in[4];
    const float* bd   = (const float*)d_in[5];
    float* out = (float*)d_out;
    unsigned* xgP = (unsigned*)d_ws;  // [64][32][2048] uint2 = 32 MB

    hipLaunchKernelGGL(xg_gemm, dim3((BB * TT) / 64), dim3(256), 0, stream,
                       X, Wx, bias, xgP);
    hipLaunchKernelGGL(lstm_rec, dim3(BB / 2), dim3(64), 0, stream,
                       xgP, Wh, Wd, bd, out);
}